// Round 4
// baseline (497.549 us; speedup 1.0000x reference)
//
#include <hip/hip_runtime.h>
#include <cstdint>
#include <cstddef>

// ---------------------------------------------------------------------------
// Problem constants (FeaturePropagationModule)
// ---------------------------------------------------------------------------
#define BATCHES   16
#define NC_PER    1024
#define NF_PER    4096
#define NC_TOT    (BATCHES * NC_PER)     // 16384
#define NF_TOT    (BATCHES * NF_PER)     // 65536
#define C_IN      512
#define C_SKIP    256
#define D_IN      (C_IN + C_SKIP)        // 768
#define C_OUT     512
#define BN_EPS    1e-5f

typedef __bf16 bf16x8 __attribute__((ext_vector_type(8)));
typedef __bf16 bf16x4 __attribute__((ext_vector_type(4)));
typedef float  f32x4  __attribute__((ext_vector_type(4)));

static_assert(sizeof(__bf16) == 2, "bf16 size");

// inline-asm 16B global load: issue point is pinned by surrounding volatile
// fences; completion is guaranteed ONLY by our manual counted vmcnt.
__device__ __forceinline__ bf16x8 load16(const __bf16* p) {
  f32x4 r;
  asm volatile("global_load_dwordx4 %0, %1, off" : "=v"(r) : "v"(p));
  union { f32x4 f; bf16x8 b; } u; u.f = r; return u.b;
}

// ---------------------------------------------------------------------------
// Kernel 1 (R7): prep = knn (blocks 0..1023) + both weight transposes
// (blocks 1024..3583). Independent work fused to cut launches.
//
// knn part: per-batch 3-NN (segmented scan, 4 segments of 256 per point).
// Distances replicate the numpy-fp32 oracle BIT-EXACTLY (per-op __f*_rn,
// numpy association order); lexicographic merge == stable ascending scan.
// ---------------------------------------------------------------------------
__global__ __launch_bounds__(256) void prep_kernel(
    const float* __restrict__ pos,      // [NC_TOT, 3]
    const float* __restrict__ pos_skip, // [NF_TOT, 3]
    int4*  __restrict__ idx3,           // [NF_TOT]
    float4* __restrict__ w3,            // [NF_TOT]
    const float* __restrict__ W1, const float* __restrict__ W2,
    __bf16* __restrict__ W1t, __bf16* __restrict__ W2t)
{
  __shared__ float s_pos[NC_PER * 3];   // 12 KiB
  __shared__ float s_pc2[NC_PER];       // 4 KiB
  __shared__ float s_pd[4][64][3];      // 3 KiB
  __shared__ int   s_pi[4][64][3];      // 3 KiB

  const int tid = threadIdx.x;

  if (blockIdx.x >= 1024) {             // ---- transpose part ----
    int idx = (blockIdx.x - 1024) * 256 + tid;
    if (idx < D_IN * C_OUT) {               // W1: K=768, N=512
      int n = idx / D_IN, k = idx - n * D_IN;
      W1t[idx] = (__bf16)W1[k * C_OUT + n];
    } else {
      idx -= D_IN * C_OUT;
      if (idx < C_OUT * C_OUT) {            // W2: K=512, N=512
        int n = idx >> 9, k = idx & 511;
        W2t[idx] = (__bf16)W2[k * C_OUT + n];
      }
    }
    return;
  }

  // ---- knn part (1024 blocks) ----
  const int bi    = blockIdx.x;
  const int fbase = bi * 64;
  const int b     = fbase >> 12;        // / NF_PER
  const int cbase = b * NC_PER;

  for (int i = tid; i < NC_PER * 3; i += 256)
    s_pos[i] = pos[(size_t)cbase * 3 + i];
  __syncthreads();
  for (int j = tid; j < NC_PER; j += 256) {
    float cx = s_pos[j * 3 + 0], cy = s_pos[j * 3 + 1], cz = s_pos[j * 3 + 2];
    s_pc2[j] = __fadd_rn(__fadd_rn(__fmul_rn(cx, cx), __fmul_rn(cy, cy)),
                         __fmul_rn(cz, cz));
  }
  __syncthreads();

  const int p   = tid & 63;
  const int seg = tid >> 6;
  const int f   = fbase + p;
  const float px = pos_skip[f * 3 + 0];
  const float py = pos_skip[f * 3 + 1];
  const float pz = pos_skip[f * 3 + 2];
  const float pf2 = __fadd_rn(__fadd_rn(__fmul_rn(px, px), __fmul_rn(py, py)),
                              __fmul_rn(pz, pz));
  float b0 = 1e30f, b1 = 1e30f, b2 = 1e30f;
  int   i0 = 0,     i1 = 0,     i2 = 0;
  const int j0 = seg * 256;
#pragma unroll 4
  for (int jj = 0; jj < 256; ++jj) {
    const int j = j0 + jj;
    float cx = s_pos[j * 3 + 0], cy = s_pos[j * 3 + 1], cz = s_pos[j * 3 + 2];
    float dot = __fadd_rn(__fadd_rn(__fmul_rn(px, cx), __fmul_rn(py, cy)),
                          __fmul_rn(pz, cz));
    float d2 = __fsub_rn(__fadd_rn(pf2, s_pc2[j]), __fmul_rn(2.0f, dot));
    if (d2 < b2) {                       // strict < keeps earliest (lowest j)
      if (d2 < b1) {
        b2 = b1; i2 = i1;
        if (d2 < b0) { b1 = b0; i1 = i0; b0 = d2; i0 = j; }
        else         { b1 = d2; i1 = j; }
      } else { b2 = d2; i2 = j; }
    }
  }
  s_pd[seg][p][0] = b0; s_pd[seg][p][1] = b1; s_pd[seg][p][2] = b2;
  s_pi[seg][p][0] = i0; s_pi[seg][p][1] = i1; s_pi[seg][p][2] = i2;
  __syncthreads();

  if (tid < 64) {
    float m0 = 1e30f, m1 = 1e30f, m2 = 1e30f;
    int  mi0 = 0,    mi1 = 0,    mi2 = 0;
#pragma unroll
    for (int s = 0; s < 4; ++s)
#pragma unroll
      for (int k = 0; k < 3; ++k) {
        float d = s_pd[s][tid][k];
        int   i = s_pi[s][tid][k];
        if (d < m2 || (d == m2 && i < mi2)) {
          if (d < m1 || (d == m1 && i < mi1)) {
            m2 = m1; mi2 = mi1;
            if (d < m0 || (d == m0 && i < mi0)) {
              m1 = m0; mi1 = mi0; m0 = d; mi0 = i;
            } else { m1 = d; mi1 = i; }
          } else { m2 = d; mi2 = i; }
        }
      }
    float w0 = 1.0f / fmaxf(m0, 1e-16f);
    float w1 = 1.0f / fmaxf(m1, 1e-16f);
    float w2 = 1.0f / fmaxf(m2, 1e-16f);
    float inv = 1.0f / __fadd_rn(__fadd_rn(w0, w1), w2);
    const int fo = fbase + tid;
    idx3[fo] = make_int4(mi0, mi1, mi2, 0);
    w3[fo]   = make_float4(w0 * inv, w1 * inv, w2 * inv, 0.f);
  }
}

// ---------------------------------------------------------------------------
// Kernel 2: gather + weighted sum + concat skip -> h0 bf16.
// One wave per fine point; XCD swizzle keeps each XCD's 2 x-slabs in its L2.
// ---------------------------------------------------------------------------
__global__ __launch_bounds__(256) void gather_interp(
    const float* __restrict__ x,        // [NC_TOT, C_IN]
    const float* __restrict__ x_skip,   // [NF_TOT, C_SKIP]
    const int4*  __restrict__ idx3,     // [NF_TOT]
    const float4* __restrict__ w3,      // [NF_TOT]
    __bf16* __restrict__ h0)            // [NF_TOT, D_IN]
{
  const int bi   = blockIdx.x;          // 16384 blocks
  const int xcd  = bi & 7;
  const int slot = bi >> 3;             // 0..2047
  const int batch = xcd * 2 + (slot >> 10);
  const int blk   = slot & 1023;
  const int wv = threadIdx.x >> 6, ln = threadIdx.x & 63;
  const int f = batch * NF_PER + blk * 4 + wv;
  const int cbase = batch * NC_PER;

  const int4   id = idx3[f];
  const float4 w  = w3[f];
  const float* x0 = x + (size_t)(cbase + id.x) * C_IN;
  const float* x1 = x + (size_t)(cbase + id.y) * C_IN;
  const float* x2 = x + (size_t)(cbase + id.z) * C_IN;
  __bf16* o = h0 + (size_t)f * D_IN;
  const int c0 = ln * 4;
#pragma unroll
  for (int it = 0; it < 2; ++it) {
    const int c = c0 + it * 256;
    float4 a0 = *(const float4*)(x0 + c);
    float4 a1 = *(const float4*)(x1 + c);
    float4 a2 = *(const float4*)(x2 + c);
    bf16x4 ov;
    ov[0] = (__bf16)(w.x * a0.x + w.y * a1.x + w.z * a2.x);
    ov[1] = (__bf16)(w.x * a0.y + w.y * a1.y + w.z * a2.y);
    ov[2] = (__bf16)(w.x * a0.z + w.y * a1.z + w.z * a2.z);
    ov[3] = (__bf16)(w.x * a0.w + w.y * a1.w + w.z * a2.w);
    *(bf16x4*)(o + c) = ov;
  }
  float4 s = *(const float4*)(x_skip + (size_t)f * C_SKIP + c0);
  bf16x4 sv;
  sv[0] = (__bf16)s.x; sv[1] = (__bf16)s.y;
  sv[2] = (__bf16)s.z; sv[3] = (__bf16)s.w;
  *(bf16x4*)(o + C_IN + c0) = sv;
}

// ---------------------------------------------------------------------------
// Kernel 3: 256x256 8-phase bf16 MFMA GEMM (unchanged from R6, known-good).
//  a) Coalesced C-store: repack the 256x256 bf16 C-tile through the dead
//     As/Bs LDS (quad-XOR swizzled, conflict-free), store bf16x8/lane.
//  b) FUSE_BN (gemm2): A reg-staged via inline-asm loads at phase 0
//     (counted vmcnt), BN1+ReLU from LDS-cached ab1, ds_write into the
//     swizzled layout. Eliminates the bnrelu_bf16 full-tensor pass.
// ---------------------------------------------------------------------------
template <int K, bool FUSE_BN>
__global__ __launch_bounds__(512, 2) void gemm_bt(
    const __bf16* __restrict__ A,    // [M, K]
    const __bf16* __restrict__ Bt,   // [512, K]
    const float*  __restrict__ bias, // [512]
    __bf16* __restrict__ Cout,       // [M, 512]
    float* __restrict__ part1,       // [256][1024] per-mblock partials
    const float* __restrict__ ab)    // [1024] BN a/b (FUSE_BN only)
{
  constexpr int NT = K / 64;                        // K-tiles (12 or 8)
  __shared__ __align__(16) __bf16 As[2 * 16384];    // [buf][half][128][64]
  __shared__ __align__(16) __bf16 Bs[2 * 16384];
  __shared__ float s_red[4][4][16][2];              // [wn][nf][l16][sum/ss]
  __shared__ float s_ab[1024];                      // BN coeffs (FUSE_BN)

  const int tid  = threadIdx.x;
  const int wave = tid >> 6, lane = tid & 63;
  const int quad = lane >> 4, l16 = lane & 15;
  const int wm = wave >> 2, wn = wave & 3;          // 2 x 4 wave grid

  // T1: XCD-chunked bijective work mapping (512 % 8 == 0).
  const int bid  = blockIdx.x;
  const int work = (bid & 7) * 64 + (bid >> 3);
  const int mt = work >> 1, nt = work & 1;
  const int m0 = mt * 256, n0 = nt * 256;

  // ---- staging geometry (T2 write side) -----------------------------------
  const int slot = lane & 7, rsub = lane >> 3;
  const int rowA = wave * 8 + rsub;                 // + q*64
  const int kSw  = (slot ^ rsub) * 8;               // swizzled k-off (elems)
  const int ldsChunkBase = (wave * 64) * 8;         // elems, + q*4096

  auto stage_half = [&](const __bf16* __restrict__ src, int rowBase, int t,
                        __bf16* dst) {
#pragma unroll
    for (int q = 0; q < 2; ++q) {
      __builtin_amdgcn_global_load_lds(
          (const __attribute__((address_space(1))) unsigned int*)(
              src + (size_t)(rowBase + q * 64 + rowA) * K + t * 64 + kSw),
          (__attribute__((address_space(3))) unsigned int*)(
              dst + q * 4096 + ldsChunkBase),
          16, 0, 0);
    }
  };

  bf16x8 ar[4];  // FUSE_BN: in-flight A tile (h*2+q)

  auto load_a_regs = [&](int tt) {
#pragma unroll
    for (int h = 0; h < 2; ++h)
#pragma unroll
      for (int q = 0; q < 2; ++q)
        ar[h * 2 + q] = load16(A + (size_t)(m0 + h * 128 + q * 64 + rowA) * K +
                               tt * 64 + slot * 8);
  };
  auto bn_write_A = [&](int tt, __bf16* dstbuf) {
    const int cb = tt * 64 + slot * 8;
    const float4 aL = *(const float4*)&s_ab[cb];
    const float4 aH = *(const float4*)&s_ab[cb + 4];
    const float4 bL = *(const float4*)&s_ab[512 + cb];
    const float4 bH = *(const float4*)&s_ab[512 + cb + 4];
#pragma unroll
    for (int i = 0; i < 4; ++i) {
      bf16x8 v = ar[i]; bf16x8 o;
      o[0] = (__bf16)fmaxf(fmaf((float)v[0], aL.x, bL.x), 0.f);
      o[1] = (__bf16)fmaxf(fmaf((float)v[1], aL.y, bL.y), 0.f);
      o[2] = (__bf16)fmaxf(fmaf((float)v[2], aL.z, bL.z), 0.f);
      o[3] = (__bf16)fmaxf(fmaf((float)v[3], aL.w, bL.w), 0.f);
      o[4] = (__bf16)fmaxf(fmaf((float)v[4], aH.x, bH.x), 0.f);
      o[5] = (__bf16)fmaxf(fmaf((float)v[5], aH.y, bH.y), 0.f);
      o[6] = (__bf16)fmaxf(fmaf((float)v[6], aH.z, bH.z), 0.f);
      o[7] = (__bf16)fmaxf(fmaf((float)v[7], aH.w, bH.w), 0.f);
      const int h = i >> 1, q = i & 1;
      *(bf16x8*)(dstbuf + h * 8192 + (size_t)(q * 64 + rowA) * 64 + kSw) = o;
    }
  };

  f32x4 acc[8][4] = {};
  const int swz  = (l16 & 7) << 3;        // T2 read-side XOR (elements)
  const int brow = (wn & 1) * 64;         // wave's row base inside its B half

  // ---- prologue: K-tile 0 -> buf 0 ----------------------------------------
  if constexpr (FUSE_BN) {
    for (int i = tid; i < 1024; i += 512) s_ab[i] = ab[i];
    load_a_regs(0);                       // 4 asm loads
    stage_half(Bt, n0,       0, Bs);      // 4 DMA
    stage_half(Bt, n0 + 128, 0, Bs + 8192);
    __syncthreads();                      // vmcnt(0)+lgkm; s_ab visible
    bn_write_A(0, As);
    asm volatile("s_waitcnt lgkmcnt(0)" ::: "memory");
    __builtin_amdgcn_sched_barrier(0);
    __builtin_amdgcn_s_barrier();
  } else {
    stage_half(A,  m0,       0, As);
    stage_half(Bt, n0,       0, Bs);
    stage_half(A,  m0 + 128, 0, As + 8192);
    stage_half(Bt, n0 + 128, 0, Bs + 8192);
  }

  bf16x8 aA[4][2], bB[4][2];
#pragma unroll 2
  for (int t = 0; t < NT; ++t) {
    const int cur = t & 1;
    const __bf16* Ab = As + (cur * 2 + wm) * 8192;         // wave's A half
    const __bf16* Bb = Bs + (cur * 2 + (wn >> 1)) * 8192;  // wave's B half
    __bf16* Asn = As + (cur ^ 1) * 16384;
    __bf16* Bsn = Bs + (cur ^ 1) * 16384;

    // ========== phase 0 : (m-half 0) x (n-frags 0,1) ==========
    if (t + 1 < NT) {
      if constexpr (FUSE_BN) {
        load_a_regs(t + 1);                              // 4 asm loads (oldest)
        stage_half(Bt, n0, t + 1, Bsn);                  // 2 DMA
        asm volatile("s_waitcnt vmcnt(6)" ::: "memory"); // drain B(t) 4 DMA
      } else {
        stage_half(A,  m0, t + 1, Asn);
        stage_half(Bt, n0, t + 1, Bsn);
        asm volatile("s_waitcnt vmcnt(4)" ::: "memory"); // drain tile t's 8
      }
    } else {
      asm volatile("s_waitcnt vmcnt(0)" ::: "memory");   // last tile drains
    }
    __builtin_amdgcn_sched_barrier(0);
    __builtin_amdgcn_s_barrier();
#pragma unroll
    for (int mf = 0; mf < 4; ++mf)
#pragma unroll
      for (int ks = 0; ks < 2; ++ks)
        aA[mf][ks] = *(const bf16x8*)(Ab + (mf * 16 + l16) * 64 +
                                      ((ks * 32 + quad * 8) ^ swz));
#pragma unroll
    for (int nf = 0; nf < 2; ++nf)
#pragma unroll
      for (int ks = 0; ks < 2; ++ks)
        bB[nf][ks] = *(const bf16x8*)(Bb + (brow + nf * 16 + l16) * 64 +
                                      ((ks * 32 + quad * 8) ^ swz));
    __builtin_amdgcn_s_setprio(1);
#pragma unroll
    for (int mf = 0; mf < 4; ++mf)
#pragma unroll
      for (int nf = 0; nf < 2; ++nf)
#pragma unroll
        for (int ks = 0; ks < 2; ++ks)
          acc[mf][nf] = __builtin_amdgcn_mfma_f32_16x16x32_bf16(
              aA[mf][ks], bB[nf][ks], acc[mf][nf], 0, 0, 0);
    __builtin_amdgcn_s_setprio(0);
    __builtin_amdgcn_s_barrier();

    // ========== phase 1 : (m-half 0) x (n-frags 2,3) ==========
    if (t + 1 < NT) {
      stage_half(Bt, n0 + 128, t + 1, Bsn + 8192);       // 2 DMA
      if constexpr (!FUSE_BN)
        stage_half(A, m0 + 128, t + 1, Asn + 8192);
    }
#pragma unroll
    for (int nf = 2; nf < 4; ++nf)
#pragma unroll
      for (int ks = 0; ks < 2; ++ks)
        bB[nf][ks] = *(const bf16x8*)(Bb + (brow + nf * 16 + l16) * 64 +
                                      ((ks * 32 + quad * 8) ^ swz));
    __builtin_amdgcn_s_setprio(1);
#pragma unroll
    for (int mf = 0; mf < 4; ++mf)
#pragma unroll
      for (int nf = 2; nf < 4; ++nf)
#pragma unroll
        for (int ks = 0; ks < 2; ++ks)
          acc[mf][nf] = __builtin_amdgcn_mfma_f32_16x16x32_bf16(
              aA[mf][ks], bB[nf][ks], acc[mf][nf], 0, 0, 0);
    __builtin_amdgcn_s_setprio(0);
    __builtin_amdgcn_s_barrier();

    // ========== phase 2 : (m-half 1) x (n-frags 0,1) ==========
#pragma unroll
    for (int mf = 0; mf < 4; ++mf)
#pragma unroll
      for (int ks = 0; ks < 2; ++ks)
        aA[mf][ks] = *(const bf16x8*)(Ab + (64 + mf * 16 + l16) * 64 +
                                      ((ks * 32 + quad * 8) ^ swz));
    __builtin_amdgcn_s_setprio(1);
#pragma unroll
    for (int mf = 0; mf < 4; ++mf)
#pragma unroll
      for (int nf = 0; nf < 2; ++nf)
#pragma unroll
        for (int ks = 0; ks < 2; ++ks)
          acc[4 + mf][nf] = __builtin_amdgcn_mfma_f32_16x16x32_bf16(
              aA[mf][ks], bB[nf][ks], acc[4 + mf][nf], 0, 0, 0);
    __builtin_amdgcn_s_setprio(0);
    __builtin_amdgcn_s_barrier();

    // ========== phase 3 : (m-half 1) x (n-frags 2,3) ==========
    __builtin_amdgcn_s_setprio(1);
#pragma unroll
    for (int mf = 0; mf < 4; ++mf)
#pragma unroll
      for (int nf = 2; nf < 4; ++nf)
#pragma unroll
        for (int ks = 0; ks < 2; ++ks)
          acc[4 + mf][nf] = __builtin_amdgcn_mfma_f32_16x16x32_bf16(
              aA[mf][ks], bB[nf][ks], acc[4 + mf][nf], 0, 0, 0);
    __builtin_amdgcn_s_setprio(0);
    if constexpr (FUSE_BN) {
      if (t + 1 < NT) {
        asm volatile("s_waitcnt vmcnt(4)" ::: "memory"); // drain A(t+1) regs
        __builtin_amdgcn_sched_barrier(0);
        bn_write_A(t + 1, Asn);
        asm volatile("s_waitcnt lgkmcnt(0)" ::: "memory");
        __builtin_amdgcn_sched_barrier(0);
      }
    }
    __builtin_amdgcn_s_barrier();
  }

  // ---- epilogue: stats (regs) + C repack through dead As/Bs ---------------
  // C/D layout (m89/m91): n = l16, m = quad*4 + r.
  // LDS repack: bf16 C[256][256]; rows<128 in As, rows>=128 in Bs; columns
  // quad-XOR swizzled (col ^ (quad<<4)) -> conflict-free b16 writes.
  float sArr[4], ssArr[4];
  {
    __bf16* cbase = wm ? Bs : As;
#pragma unroll
    for (int nf = 0; nf < 4; ++nf) {
      const int cl = wn * 64 + nf * 16 + l16;            // block-local col
      const float bv = bias[n0 + cl];
      float s = 0.f, ss = 0.f;
#pragma unroll
      for (int mf = 0; mf < 8; ++mf) {
        const int rl = (wm * 128 + mf * 16 + quad * 4) & 127;
#pragma unroll
        for (int r = 0; r < 4; ++r) {
          const float v = acc[mf][nf][r] + bv;
          s += v; ss += v * v;
          cbase[(rl + r) * 256 + (cl ^ (quad << 4))] = (__bf16)v;
        }
      }
      s  += __shfl_down(s, 32);  s  += __shfl_down(s, 16);
      ss += __shfl_down(ss, 32); ss += __shfl_down(ss, 16);
      sArr[nf] = s; ssArr[nf] = ss;
    }
  }
  if (wm == 1 && quad == 0) {
#pragma unroll
    for (int nf = 0; nf < 4; ++nf) {
      s_red[wn][nf][l16][0] = sArr[nf];
      s_red[wn][nf][l16][1] = ssArr[nf];
    }
  }
  __syncthreads();

  // coalesced C store: 16 passes x 512 thr x 16B = 256x256 bf16
#pragma unroll
  for (int p = 0; p < 16; ++p) {
    const int i   = p * 512 + tid;
    const int row = i >> 5;                 // 0..255
    const int cc  = (i & 31) * 8;           // elem col base
    const __bf16* base = (p < 8) ? As : Bs;
    bf16x8 v = *(const bf16x8*)&base[(row & 127) * 256 +
                                     (cc ^ (((row >> 2) & 3) << 4))];
    *(bf16x8*)&Cout[(size_t)(m0 + row) * 512 + n0 + cc] = v;
  }

  if (wm == 0 && quad == 0) {
    float* rowp = part1 + (size_t)mt * 1024;
#pragma unroll
    for (int nf = 0; nf < 4; ++nf) {
      const int n = n0 + wn * 64 + nf * 16 + l16;
      rowp[n]       = sArr[nf]  + s_red[wn][nf][l16][0];
      rowp[512 + n] = ssArr[nf] + s_red[wn][nf][l16][1];
    }
  }
}

// ---------------------------------------------------------------------------
// Kernel 4 (R7): fused stats: part1[256][1024] -> BN coefficients ab[1024].
// 2 blocks x 256 threads; thread owns column c, sums all 256 rows directly.
// ab layout: [0,512) = scale a, [512,1024) = shift b:  y = a*h + b
// ---------------------------------------------------------------------------
__global__ __launch_bounds__(256) void stats_kernel(
    const float* __restrict__ part1,
    const float* __restrict__ g, const float* __restrict__ be,
    float* __restrict__ ab, float invM) {
  const int c = blockIdx.x * 256 + threadIdx.x;   // 0..511
  const float* p = part1 + c;
  float s0 = 0.f, s1 = 0.f, ss0 = 0.f, ss1 = 0.f;
#pragma unroll 4
  for (int r = 0; r < 256; r += 2) {
    s0  += p[(size_t)r * 1024];
    s1  += p[(size_t)(r + 1) * 1024];
    ss0 += p[(size_t)r * 1024 + 512];
    ss1 += p[(size_t)(r + 1) * 1024 + 512];
  }
  const float s = s0 + s1, ss = ss0 + ss1;
  const float mean = s * invM;
  const float var  = ss * invM - mean * mean;
  const float a = g[c] * rsqrtf(var + BN_EPS);
  ab[c] = a;
  ab[512 + c] = be[c] - mean * a;
}

// ---------------------------------------------------------------------------
// Kernel 5 (R7): BN+ReLU (bf16 h2 -> f32 out, 8 elems/thread) + tail
// (pos_skip copy + batch ids) in the same launch (extra 1024 blocks).
// ---------------------------------------------------------------------------
__global__ __launch_bounds__(256) void bnrelu_tail(
    const __bf16* __restrict__ H, const float* __restrict__ ab,
    float* __restrict__ O,
    const float* __restrict__ pos_skip, float* __restrict__ out2) {
  if (blockIdx.x >= 16384) {              // ---- tail part ----
    const int i = (blockIdx.x - 16384) * 256 + threadIdx.x;  // 0..262143
    if (i < NF_TOT * 3) {
      out2[i] = pos_skip[i];
    } else {
      const int f = i - NF_TOT * 3;
      out2[i] = (float)(f >> 12);         // f / NF_PER
    }
    return;
  }
  const size_t e = ((size_t)blockIdx.x * 256 + threadIdx.x) * 8;
  const int c = (int)(e & 511);
  bf16x8 h = *(const bf16x8*)(H + e);
  float4 o0, o1;
  o0.x = fmaxf(fmaf((float)h[0], ab[c + 0], ab[512 + c + 0]), 0.f);
  o0.y = fmaxf(fmaf((float)h[1], ab[c + 1], ab[512 + c + 1]), 0.f);
  o0.z = fmaxf(fmaf((float)h[2], ab[c + 2], ab[512 + c + 2]), 0.f);
  o0.w = fmaxf(fmaf((float)h[3], ab[c + 3], ab[512 + c + 3]), 0.f);
  o1.x = fmaxf(fmaf((float)h[4], ab[c + 4], ab[512 + c + 4]), 0.f);
  o1.y = fmaxf(fmaf((float)h[5], ab[c + 5], ab[512 + c + 5]), 0.f);
  o1.z = fmaxf(fmaf((float)h[6], ab[c + 6], ab[512 + c + 6]), 0.f);
  o1.w = fmaxf(fmaf((float)h[7], ab[c + 7], ab[512 + c + 7]), 0.f);
  *(float4*)(O + e)     = o0;
  *(float4*)(O + e + 4) = o1;
}

// ---------------------------------------------------------------------------
// Launch (7 dispatches)
// ---------------------------------------------------------------------------
extern "C" void kernel_launch(void* const* d_in, const int* in_sizes, int n_in,
                              void* d_out, int out_size, void* d_ws, size_t ws_size,
                              hipStream_t stream) {
  (void)in_sizes; (void)n_in; (void)out_size; (void)ws_size;

  const float* x        = (const float*)d_in[0];
  const float* pos      = (const float*)d_in[1];
  const float* x_skip   = (const float*)d_in[3];
  const float* pos_skip = (const float*)d_in[4];
  const float* W1  = (const float*)d_in[6];
  const float* b1  = (const float*)d_in[7];
  const float* g1  = (const float*)d_in[8];
  const float* be1 = (const float*)d_in[9];
  const float* W2  = (const float*)d_in[10];
  const float* b2  = (const float*)d_in[11];
  const float* g2  = (const float*)d_in[12];
  const float* be2 = (const float*)d_in[13];
  float* out = (float*)d_out;

  char* ws = (char*)d_ws;
  // workspace layout (bytes). h2 aliases h0 (h0 dead after gemm1).
  // part1 reuses the idx3/w3 region (dead after gather_interp).
  __bf16* h0   = (__bf16*)(ws);                          // 100,663,296  h0 [65536,768]
  __bf16* h2   = (__bf16*)(ws);                          //  67,108,864  h2 [65536,512]
  __bf16* h1   = (__bf16*)(ws + 100663296ull);           //  67,108,864  h1 [65536,512] (RAW gemm1 out)
  __bf16* W1t  = (__bf16*)(ws + 167772160ull);           //     786,432  [512,768]
  __bf16* W2t  = (__bf16*)(ws + 168558592ull);           //     524,288  [512,512]
  float*  ab1   = (float*)(ws + 169086976ull);           //       4,096
  float*  ab2   = (float*)(ws + 169095168ull);           //       4,096
  int4*   idx3  = (int4*)(ws + 169099264ull);            //   1,048,576  [65536]
  float4* w3    = (float4*)(ws + 170147840ull);          //   1,048,576  [65536]
  float*  part1 = (float*)(ws + 169099264ull);           //   1,048,576  aliases idx3
  float*  part2 = (float*)(ws + 171196416ull);           //      65,536  (unused, kept for layout stability)
  (void)part2;

  // prep: knn (1024 blocks) + both weight transposes (2560 blocks)
  prep_kernel<<<1024 + (D_IN * C_OUT + C_OUT * C_OUT + 255) / 256, 256, 0, stream>>>(
      pos, pos_skip, idx3, w3, W1, W2, W1t, W2t);

  // gather+concat -> h0
  gather_interp<<<NF_TOT / 4, 256, 0, stream>>>(x, x_skip, idx3, w3, h0);

  // layer 1: gemm (+fused partial stats) -> bn coeffs
  gemm_bt<D_IN, false><<<512, 512, 0, stream>>>(h0, W1t, b1, h1, part1, nullptr);
  stats_kernel<<<2, 256, 0, stream>>>(part1, g1, be1, ab1, 1.0f / (float)NF_TOT);

  // layer 2: gemm with BN1+ReLU fused into A-staging -> bf16 h2 (+stats)
  gemm_bt<C_OUT, true><<<512, 512, 0, stream>>>(h1, W2t, b2, h2, part1, ab1);
  stats_kernel<<<2, 256, 0, stream>>>(part1, g2, be2, ab2, 1.0f / (float)NF_TOT);

  // BN2+ReLU -> f32 out, plus pos_skip/batch tail in extra blocks
  bnrelu_tail<<<16384 + 1024, 256, 0, stream>>>(
      h2, ab2, out, pos_skip, out + (size_t)NF_TOT * 512);
}

// Round 5
// 462.813 us; speedup vs baseline: 1.0751x; 1.0751x over previous
//
#include <hip/hip_runtime.h>
#include <cstdint>
#include <cstddef>

// ---------------------------------------------------------------------------
// Problem constants (FeaturePropagationModule)
// ---------------------------------------------------------------------------
#define BATCHES   16
#define NC_PER    1024
#define NF_PER    4096
#define NC_TOT    (BATCHES * NC_PER)     // 16384
#define NF_TOT    (BATCHES * NF_PER)     // 65536
#define C_IN      512
#define C_SKIP    256
#define D_IN      (C_IN + C_SKIP)        // 768
#define C_OUT     512
#define BN_EPS    1e-5f

typedef __bf16 bf16x8 __attribute__((ext_vector_type(8)));
typedef __bf16 bf16x4 __attribute__((ext_vector_type(4)));
typedef float  f32x4  __attribute__((ext_vector_type(4)));

static_assert(sizeof(__bf16) == 2, "bf16 size");

// inline-asm 16B global load: issue point is pinned by surrounding volatile
// fences; completion is guaranteed ONLY by our manual counted vmcnt.
__device__ __forceinline__ bf16x8 load16(const __bf16* p) {
  f32x4 r;
  asm volatile("global_load_dwordx4 %0, %1, off" : "=v"(r) : "v"(p));
  union { f32x4 f; bf16x8 b; } u; u.f = r; return u.b;
}

// ---------------------------------------------------------------------------
// Kernel 1: prep = knn (blocks 0..1023) + both weight transposes
// (blocks 1024..3583). Independent work fused to cut launches.
//
// knn part: per-batch 3-NN (segmented scan, 4 segments of 256 per point).
// Distances replicate the numpy-fp32 oracle BIT-EXACTLY (per-op __f*_rn,
// numpy association order); lexicographic merge == stable ascending scan.
// ---------------------------------------------------------------------------
__global__ __launch_bounds__(256) void prep_kernel(
    const float* __restrict__ pos,      // [NC_TOT, 3]
    const float* __restrict__ pos_skip, // [NF_TOT, 3]
    int4*  __restrict__ idx3,           // [NF_TOT]
    float4* __restrict__ w3,            // [NF_TOT]
    const float* __restrict__ W1, const float* __restrict__ W2,
    __bf16* __restrict__ W1t, __bf16* __restrict__ W2t)
{
  __shared__ float s_pos[NC_PER * 3];   // 12 KiB
  __shared__ float s_pc2[NC_PER];       // 4 KiB
  __shared__ float s_pd[4][64][3];      // 3 KiB
  __shared__ int   s_pi[4][64][3];      // 3 KiB

  const int tid = threadIdx.x;

  if (blockIdx.x >= 1024) {             // ---- transpose part ----
    int idx = (blockIdx.x - 1024) * 256 + tid;
    if (idx < D_IN * C_OUT) {               // W1: K=768, N=512
      int n = idx / D_IN, k = idx - n * D_IN;
      W1t[idx] = (__bf16)W1[k * C_OUT + n];
    } else {
      idx -= D_IN * C_OUT;
      if (idx < C_OUT * C_OUT) {            // W2: K=512, N=512
        int n = idx >> 9, k = idx & 511;
        W2t[idx] = (__bf16)W2[k * C_OUT + n];
      }
    }
    return;
  }

  // ---- knn part (1024 blocks) ----
  const int bi    = blockIdx.x;
  const int fbase = bi * 64;
  const int b     = fbase >> 12;        // / NF_PER
  const int cbase = b * NC_PER;

  for (int i = tid; i < NC_PER * 3; i += 256)
    s_pos[i] = pos[(size_t)cbase * 3 + i];
  __syncthreads();
  for (int j = tid; j < NC_PER; j += 256) {
    float cx = s_pos[j * 3 + 0], cy = s_pos[j * 3 + 1], cz = s_pos[j * 3 + 2];
    s_pc2[j] = __fadd_rn(__fadd_rn(__fmul_rn(cx, cx), __fmul_rn(cy, cy)),
                         __fmul_rn(cz, cz));
  }
  __syncthreads();

  const int p   = tid & 63;
  const int seg = tid >> 6;
  const int f   = fbase + p;
  const float px = pos_skip[f * 3 + 0];
  const float py = pos_skip[f * 3 + 1];
  const float pz = pos_skip[f * 3 + 2];
  const float pf2 = __fadd_rn(__fadd_rn(__fmul_rn(px, px), __fmul_rn(py, py)),
                              __fmul_rn(pz, pz));
  float b0 = 1e30f, b1 = 1e30f, b2 = 1e30f;
  int   i0 = 0,     i1 = 0,     i2 = 0;
  const int j0 = seg * 256;
#pragma unroll 4
  for (int jj = 0; jj < 256; ++jj) {
    const int j = j0 + jj;
    float cx = s_pos[j * 3 + 0], cy = s_pos[j * 3 + 1], cz = s_pos[j * 3 + 2];
    float dot = __fadd_rn(__fadd_rn(__fmul_rn(px, cx), __fmul_rn(py, cy)),
                          __fmul_rn(pz, cz));
    float d2 = __fsub_rn(__fadd_rn(pf2, s_pc2[j]), __fmul_rn(2.0f, dot));
    if (d2 < b2) {                       // strict < keeps earliest (lowest j)
      if (d2 < b1) {
        b2 = b1; i2 = i1;
        if (d2 < b0) { b1 = b0; i1 = i0; b0 = d2; i0 = j; }
        else         { b1 = d2; i1 = j; }
      } else { b2 = d2; i2 = j; }
    }
  }
  s_pd[seg][p][0] = b0; s_pd[seg][p][1] = b1; s_pd[seg][p][2] = b2;
  s_pi[seg][p][0] = i0; s_pi[seg][p][1] = i1; s_pi[seg][p][2] = i2;
  __syncthreads();

  if (tid < 64) {
    float m0 = 1e30f, m1 = 1e30f, m2 = 1e30f;
    int  mi0 = 0,    mi1 = 0,    mi2 = 0;
#pragma unroll
    for (int s = 0; s < 4; ++s)
#pragma unroll
      for (int k = 0; k < 3; ++k) {
        float d = s_pd[s][tid][k];
        int   i = s_pi[s][tid][k];
        if (d < m2 || (d == m2 && i < mi2)) {
          if (d < m1 || (d == m1 && i < mi1)) {
            m2 = m1; mi2 = mi1;
            if (d < m0 || (d == m0 && i < mi0)) {
              m1 = m0; mi1 = mi0; m0 = d; mi0 = i;
            } else { m1 = d; mi1 = i; }
          } else { m2 = d; mi2 = i; }
        }
      }
    float w0 = 1.0f / fmaxf(m0, 1e-16f);
    float w1 = 1.0f / fmaxf(m1, 1e-16f);
    float w2 = 1.0f / fmaxf(m2, 1e-16f);
    float inv = 1.0f / __fadd_rn(__fadd_rn(w0, w1), w2);
    const int fo = fbase + tid;
    idx3[fo] = make_int4(mi0, mi1, mi2, 0);
    w3[fo]   = make_float4(w0 * inv, w1 * inv, w2 * inv, 0.f);
  }
}

// ---------------------------------------------------------------------------
// Kernel 2: gather + weighted sum + concat skip -> h0 bf16.
// One wave per fine point; XCD swizzle keeps each XCD's 2 x-slabs in its L2.
// ---------------------------------------------------------------------------
__global__ __launch_bounds__(256) void gather_interp(
    const float* __restrict__ x,        // [NC_TOT, C_IN]
    const float* __restrict__ x_skip,   // [NF_TOT, C_SKIP]
    const int4*  __restrict__ idx3,     // [NF_TOT]
    const float4* __restrict__ w3,      // [NF_TOT]
    __bf16* __restrict__ h0)            // [NF_TOT, D_IN]
{
  const int bi   = blockIdx.x;          // 16384 blocks
  const int xcd  = bi & 7;
  const int slot = bi >> 3;             // 0..2047
  const int batch = xcd * 2 + (slot >> 10);
  const int blk   = slot & 1023;
  const int wv = threadIdx.x >> 6, ln = threadIdx.x & 63;
  const int f = batch * NF_PER + blk * 4 + wv;
  const int cbase = batch * NC_PER;

  const int4   id = idx3[f];
  const float4 w  = w3[f];
  const float* x0 = x + (size_t)(cbase + id.x) * C_IN;
  const float* x1 = x + (size_t)(cbase + id.y) * C_IN;
  const float* x2 = x + (size_t)(cbase + id.z) * C_IN;
  __bf16* o = h0 + (size_t)f * D_IN;
  const int c0 = ln * 4;
#pragma unroll
  for (int it = 0; it < 2; ++it) {
    const int c = c0 + it * 256;
    float4 a0 = *(const float4*)(x0 + c);
    float4 a1 = *(const float4*)(x1 + c);
    float4 a2 = *(const float4*)(x2 + c);
    bf16x4 ov;
    ov[0] = (__bf16)(w.x * a0.x + w.y * a1.x + w.z * a2.x);
    ov[1] = (__bf16)(w.x * a0.y + w.y * a1.y + w.z * a2.y);
    ov[2] = (__bf16)(w.x * a0.z + w.y * a1.z + w.z * a2.z);
    ov[3] = (__bf16)(w.x * a0.w + w.y * a1.w + w.z * a2.w);
    *(bf16x4*)(o + c) = ov;
  }
  float4 s = *(const float4*)(x_skip + (size_t)f * C_SKIP + c0);
  bf16x4 sv;
  sv[0] = (__bf16)s.x; sv[1] = (__bf16)s.y;
  sv[2] = (__bf16)s.z; sv[3] = (__bf16)s.w;
  *(bf16x4*)(o + C_IN + c0) = sv;
}

// ---------------------------------------------------------------------------
// Kernel 3: 256x256 8-phase bf16 MFMA GEMM (unchanged from R6, known-good).
//  a) Coalesced C-store: repack the 256x256 bf16 C-tile through the dead
//     As/Bs LDS (quad-XOR swizzled, conflict-free), store bf16x8/lane.
//  b) FUSE_BN (gemm2): A reg-staged via inline-asm loads at phase 0
//     (counted vmcnt), BN1+ReLU from LDS-cached ab1, ds_write into the
//     swizzled layout. Eliminates the bnrelu_bf16 full-tensor pass.
// ---------------------------------------------------------------------------
template <int K, bool FUSE_BN>
__global__ __launch_bounds__(512, 2) void gemm_bt(
    const __bf16* __restrict__ A,    // [M, K]
    const __bf16* __restrict__ Bt,   // [512, K]
    const float*  __restrict__ bias, // [512]
    __bf16* __restrict__ Cout,       // [M, 512]
    float* __restrict__ part1,       // [256][1024] per-mblock partials
    const float* __restrict__ ab)    // [1024] BN a/b (FUSE_BN only)
{
  constexpr int NT = K / 64;                        // K-tiles (12 or 8)
  __shared__ __align__(16) __bf16 As[2 * 16384];    // [buf][half][128][64]
  __shared__ __align__(16) __bf16 Bs[2 * 16384];
  __shared__ float s_red[4][4][16][2];              // [wn][nf][l16][sum/ss]
  __shared__ float s_ab[1024];                      // BN coeffs (FUSE_BN)

  const int tid  = threadIdx.x;
  const int wave = tid >> 6, lane = tid & 63;
  const int quad = lane >> 4, l16 = lane & 15;
  const int wm = wave >> 2, wn = wave & 3;          // 2 x 4 wave grid

  // T1: XCD-chunked bijective work mapping (512 % 8 == 0).
  const int bid  = blockIdx.x;
  const int work = (bid & 7) * 64 + (bid >> 3);
  const int mt = work >> 1, nt = work & 1;
  const int m0 = mt * 256, n0 = nt * 256;

  // ---- staging geometry (T2 write side) -----------------------------------
  const int slot = lane & 7, rsub = lane >> 3;
  const int rowA = wave * 8 + rsub;                 // + q*64
  const int kSw  = (slot ^ rsub) * 8;               // swizzled k-off (elems)
  const int ldsChunkBase = (wave * 64) * 8;         // elems, + q*4096

  auto stage_half = [&](const __bf16* __restrict__ src, int rowBase, int t,
                        __bf16* dst) {
#pragma unroll
    for (int q = 0; q < 2; ++q) {
      __builtin_amdgcn_global_load_lds(
          (const __attribute__((address_space(1))) unsigned int*)(
              src + (size_t)(rowBase + q * 64 + rowA) * K + t * 64 + kSw),
          (__attribute__((address_space(3))) unsigned int*)(
              dst + q * 4096 + ldsChunkBase),
          16, 0, 0);
    }
  };

  bf16x8 ar[4];  // FUSE_BN: in-flight A tile (h*2+q)

  auto load_a_regs = [&](int tt) {
#pragma unroll
    for (int h = 0; h < 2; ++h)
#pragma unroll
      for (int q = 0; q < 2; ++q)
        ar[h * 2 + q] = load16(A + (size_t)(m0 + h * 128 + q * 64 + rowA) * K +
                               tt * 64 + slot * 8);
  };
  auto bn_write_A = [&](int tt, __bf16* dstbuf) {
    const int cb = tt * 64 + slot * 8;
    const float4 aL = *(const float4*)&s_ab[cb];
    const float4 aH = *(const float4*)&s_ab[cb + 4];
    const float4 bL = *(const float4*)&s_ab[512 + cb];
    const float4 bH = *(const float4*)&s_ab[512 + cb + 4];
#pragma unroll
    for (int i = 0; i < 4; ++i) {
      bf16x8 v = ar[i]; bf16x8 o;
      o[0] = (__bf16)fmaxf(fmaf((float)v[0], aL.x, bL.x), 0.f);
      o[1] = (__bf16)fmaxf(fmaf((float)v[1], aL.y, bL.y), 0.f);
      o[2] = (__bf16)fmaxf(fmaf((float)v[2], aL.z, bL.z), 0.f);
      o[3] = (__bf16)fmaxf(fmaf((float)v[3], aL.w, bL.w), 0.f);
      o[4] = (__bf16)fmaxf(fmaf((float)v[4], aH.x, bH.x), 0.f);
      o[5] = (__bf16)fmaxf(fmaf((float)v[5], aH.y, bH.y), 0.f);
      o[6] = (__bf16)fmaxf(fmaf((float)v[6], aH.z, bH.z), 0.f);
      o[7] = (__bf16)fmaxf(fmaf((float)v[7], aH.w, bH.w), 0.f);
      const int h = i >> 1, q = i & 1;
      *(bf16x8*)(dstbuf + h * 8192 + (size_t)(q * 64 + rowA) * 64 + kSw) = o;
    }
  };

  f32x4 acc[8][4] = {};
  const int swz  = (l16 & 7) << 3;        // T2 read-side XOR (elements)
  const int brow = (wn & 1) * 64;         // wave's row base inside its B half

  // ---- prologue: K-tile 0 -> buf 0 ----------------------------------------
  if constexpr (FUSE_BN) {
    for (int i = tid; i < 1024; i += 512) s_ab[i] = ab[i];
    load_a_regs(0);                       // 4 asm loads
    stage_half(Bt, n0,       0, Bs);      // 4 DMA
    stage_half(Bt, n0 + 128, 0, Bs + 8192);
    __syncthreads();                      // vmcnt(0)+lgkm; s_ab visible
    bn_write_A(0, As);
    asm volatile("s_waitcnt lgkmcnt(0)" ::: "memory");
    __builtin_amdgcn_sched_barrier(0);
    __builtin_amdgcn_s_barrier();
  } else {
    stage_half(A,  m0,       0, As);
    stage_half(Bt, n0,       0, Bs);
    stage_half(A,  m0 + 128, 0, As + 8192);
    stage_half(Bt, n0 + 128, 0, Bs + 8192);
  }

  bf16x8 aA[4][2], bB[4][2];
#pragma unroll 2
  for (int t = 0; t < NT; ++t) {
    const int cur = t & 1;
    const __bf16* Ab = As + (cur * 2 + wm) * 8192;         // wave's A half
    const __bf16* Bb = Bs + (cur * 2 + (wn >> 1)) * 8192;  // wave's B half
    __bf16* Asn = As + (cur ^ 1) * 16384;
    __bf16* Bsn = Bs + (cur ^ 1) * 16384;

    // ========== phase 0 : (m-half 0) x (n-frags 0,1) ==========
    if (t + 1 < NT) {
      if constexpr (FUSE_BN) {
        load_a_regs(t + 1);                              // 4 asm loads (oldest)
        stage_half(Bt, n0, t + 1, Bsn);                  // 2 DMA
        asm volatile("s_waitcnt vmcnt(6)" ::: "memory"); // drain B(t) 4 DMA
      } else {
        stage_half(A,  m0, t + 1, Asn);
        stage_half(Bt, n0, t + 1, Bsn);
        asm volatile("s_waitcnt vmcnt(4)" ::: "memory"); // drain tile t's 8
      }
    } else {
      asm volatile("s_waitcnt vmcnt(0)" ::: "memory");   // last tile drains
    }
    __builtin_amdgcn_sched_barrier(0);
    __builtin_amdgcn_s_barrier();
#pragma unroll
    for (int mf = 0; mf < 4; ++mf)
#pragma unroll
      for (int ks = 0; ks < 2; ++ks)
        aA[mf][ks] = *(const bf16x8*)(Ab + (mf * 16 + l16) * 64 +
                                      ((ks * 32 + quad * 8) ^ swz));
#pragma unroll
    for (int nf = 0; nf < 2; ++nf)
#pragma unroll
      for (int ks = 0; ks < 2; ++ks)
        bB[nf][ks] = *(const bf16x8*)(Bb + (brow + nf * 16 + l16) * 64 +
                                      ((ks * 32 + quad * 8) ^ swz));
    __builtin_amdgcn_s_setprio(1);
#pragma unroll
    for (int mf = 0; mf < 4; ++mf)
#pragma unroll
      for (int nf = 0; nf < 2; ++nf)
#pragma unroll
        for (int ks = 0; ks < 2; ++ks)
          acc[mf][nf] = __builtin_amdgcn_mfma_f32_16x16x32_bf16(
              aA[mf][ks], bB[nf][ks], acc[mf][nf], 0, 0, 0);
    __builtin_amdgcn_s_setprio(0);
    __builtin_amdgcn_s_barrier();

    // ========== phase 1 : (m-half 0) x (n-frags 2,3) ==========
    if (t + 1 < NT) {
      stage_half(Bt, n0 + 128, t + 1, Bsn + 8192);       // 2 DMA
      if constexpr (!FUSE_BN)
        stage_half(A, m0 + 128, t + 1, Asn + 8192);
    }
#pragma unroll
    for (int nf = 2; nf < 4; ++nf)
#pragma unroll
      for (int ks = 0; ks < 2; ++ks)
        bB[nf][ks] = *(const bf16x8*)(Bb + (brow + nf * 16 + l16) * 64 +
                                      ((ks * 32 + quad * 8) ^ swz));
    __builtin_amdgcn_s_setprio(1);
#pragma unroll
    for (int mf = 0; mf < 4; ++mf)
#pragma unroll
      for (int nf = 2; nf < 4; ++nf)
#pragma unroll
        for (int ks = 0; ks < 2; ++ks)
          acc[mf][nf] = __builtin_amdgcn_mfma_f32_16x16x32_bf16(
              aA[mf][ks], bB[nf][ks], acc[mf][nf], 0, 0, 0);
    __builtin_amdgcn_s_setprio(0);
    __builtin_amdgcn_s_barrier();

    // ========== phase 2 : (m-half 1) x (n-frags 0,1) ==========
#pragma unroll
    for (int mf = 0; mf < 4; ++mf)
#pragma unroll
      for (int ks = 0; ks < 2; ++ks)
        aA[mf][ks] = *(const bf16x8*)(Ab + (64 + mf * 16 + l16) * 64 +
                                      ((ks * 32 + quad * 8) ^ swz));
    __builtin_amdgcn_s_setprio(1);
#pragma unroll
    for (int mf = 0; mf < 4; ++mf)
#pragma unroll
      for (int nf = 0; nf < 2; ++nf)
#pragma unroll
        for (int ks = 0; ks < 2; ++ks)
          acc[4 + mf][nf] = __builtin_amdgcn_mfma_f32_16x16x32_bf16(
              aA[mf][ks], bB[nf][ks], acc[4 + mf][nf], 0, 0, 0);
    __builtin_amdgcn_s_setprio(0);
    __builtin_amdgcn_s_barrier();

    // ========== phase 3 : (m-half 1) x (n-frags 2,3) ==========
    __builtin_amdgcn_s_setprio(1);
#pragma unroll
    for (int mf = 0; mf < 4; ++mf)
#pragma unroll
      for (int nf = 2; nf < 4; ++nf)
#pragma unroll
        for (int ks = 0; ks < 2; ++ks)
          acc[4 + mf][nf] = __builtin_amdgcn_mfma_f32_16x16x32_bf16(
              aA[mf][ks], bB[nf][ks], acc[4 + mf][nf], 0, 0, 0);
    __builtin_amdgcn_s_setprio(0);
    if constexpr (FUSE_BN) {
      if (t + 1 < NT) {
        asm volatile("s_waitcnt vmcnt(4)" ::: "memory"); // drain A(t+1) regs
        __builtin_amdgcn_sched_barrier(0);
        bn_write_A(t + 1, Asn);
        asm volatile("s_waitcnt lgkmcnt(0)" ::: "memory");
        __builtin_amdgcn_sched_barrier(0);
      }
    }
    __builtin_amdgcn_s_barrier();
  }

  // ---- epilogue: stats (regs) + C repack through dead As/Bs ---------------
  // C/D layout (m89/m91): n = l16, m = quad*4 + r.
  // LDS repack: bf16 C[256][256]; rows<128 in As, rows>=128 in Bs; columns
  // quad-XOR swizzled (col ^ (quad<<4)) -> conflict-free b16 writes.
  float sArr[4], ssArr[4];
  {
    __bf16* cbase = wm ? Bs : As;
#pragma unroll
    for (int nf = 0; nf < 4; ++nf) {
      const int cl = wn * 64 + nf * 16 + l16;            // block-local col
      const float bv = bias[n0 + cl];
      float s = 0.f, ss = 0.f;
#pragma unroll
      for (int mf = 0; mf < 8; ++mf) {
        const int rl = (wm * 128 + mf * 16 + quad * 4) & 127;
#pragma unroll
        for (int r = 0; r < 4; ++r) {
          const float v = acc[mf][nf][r] + bv;
          s += v; ss += v * v;
          cbase[(rl + r) * 256 + (cl ^ (quad << 4))] = (__bf16)v;
        }
      }
      s  += __shfl_down(s, 32);  s  += __shfl_down(s, 16);
      ss += __shfl_down(ss, 32); ss += __shfl_down(ss, 16);
      sArr[nf] = s; ssArr[nf] = ss;
    }
  }
  if (wm == 1 && quad == 0) {
#pragma unroll
    for (int nf = 0; nf < 4; ++nf) {
      s_red[wn][nf][l16][0] = sArr[nf];
      s_red[wn][nf][l16][1] = ssArr[nf];
    }
  }
  __syncthreads();

  // coalesced C store: 16 passes x 512 thr x 16B = 256x256 bf16
#pragma unroll
  for (int p = 0; p < 16; ++p) {
    const int i   = p * 512 + tid;
    const int row = i >> 5;                 // 0..255
    const int cc  = (i & 31) * 8;           // elem col base
    const __bf16* base = (p < 8) ? As : Bs;
    bf16x8 v = *(const bf16x8*)&base[(row & 127) * 256 +
                                     (cc ^ (((row >> 2) & 3) << 4))];
    *(bf16x8*)&Cout[(size_t)(m0 + row) * 512 + n0 + cc] = v;
  }

  if (wm == 0 && quad == 0) {
    float* rowp = part1 + (size_t)mt * 1024;
#pragma unroll
    for (int nf = 0; nf < 4; ++nf) {
      const int n = n0 + wn * 64 + nf * 16 + l16;
      rowp[n]       = sArr[nf]  + s_red[wn][nf][l16][0];
      rowp[512 + n] = ssArr[nf] + s_red[wn][nf][l16][1];
    }
  }
}

// ---------------------------------------------------------------------------
// Stage A: fold part1[256][1024] -> part2[16][1024] (coalesced, 16 blocks)
// ---------------------------------------------------------------------------
__global__ __launch_bounds__(256) void reduce_partials(
    const float* __restrict__ part1, float* __restrict__ part2) {
  const int rb = blockIdx.x;            // 16 blocks, 16 rows each
  const int t  = threadIdx.x;
#pragma unroll
  for (int k = 0; k < 4; ++k) {
    const int c = k * 256 + t;
    float acc = 0.f;
    const float* p = part1 + (size_t)rb * 16 * 1024 + c;
#pragma unroll
    for (int r = 0; r < 16; ++r) { acc += *p; p += 1024; }
    part2[rb * 1024 + c] = acc;
  }
}

// ab layout: [0,512) = scale a, [512,1024) = shift b:  y = a*h + b
__global__ void finalize_stats(const float* __restrict__ part2,
                               const float* __restrict__ g,
                               const float* __restrict__ be,
                               float* __restrict__ ab, float invM) {
  const int c = blockIdx.x * 256 + threadIdx.x;
  if (c < 512) {
    float s = 0.f, ss = 0.f;
#pragma unroll
    for (int r = 0; r < 16; ++r) {
      s  += part2[r * 1024 + c];
      ss += part2[r * 1024 + 512 + c];
    }
    float mean = s * invM;
    float var  = ss * invM - mean * mean;
    float a = g[c] * rsqrtf(var + BN_EPS);
    ab[c] = a;
    ab[512 + c] = be[c] - mean * a;
  }
}

// ---------------------------------------------------------------------------
// Kernel 5: BN+ReLU (bf16 h2 -> f32 out, 8 elems/thread) + tail
// (pos_skip copy + batch ids) in the same launch (extra 1024 blocks).
// ---------------------------------------------------------------------------
__global__ __launch_bounds__(256) void bnrelu_tail(
    const __bf16* __restrict__ H, const float* __restrict__ ab,
    float* __restrict__ O,
    const float* __restrict__ pos_skip, float* __restrict__ out2) {
  if (blockIdx.x >= 16384) {              // ---- tail part ----
    const int i = (blockIdx.x - 16384) * 256 + threadIdx.x;  // 0..262143
    if (i < NF_TOT * 3) {
      out2[i] = pos_skip[i];
    } else {
      const int f = i - NF_TOT * 3;
      out2[i] = (float)(f >> 12);         // f / NF_PER
    }
    return;
  }
  const size_t e = ((size_t)blockIdx.x * 256 + threadIdx.x) * 8;
  const int c = (int)(e & 511);
  bf16x8 h = *(const bf16x8*)(H + e);
  float4 o0, o1;
  o0.x = fmaxf(fmaf((float)h[0], ab[c + 0], ab[512 + c + 0]), 0.f);
  o0.y = fmaxf(fmaf((float)h[1], ab[c + 1], ab[512 + c + 1]), 0.f);
  o0.z = fmaxf(fmaf((float)h[2], ab[c + 2], ab[512 + c + 2]), 0.f);
  o0.w = fmaxf(fmaf((float)h[3], ab[c + 3], ab[512 + c + 3]), 0.f);
  o1.x = fmaxf(fmaf((float)h[4], ab[c + 4], ab[512 + c + 4]), 0.f);
  o1.y = fmaxf(fmaf((float)h[5], ab[c + 5], ab[512 + c + 5]), 0.f);
  o1.z = fmaxf(fmaf((float)h[6], ab[c + 6], ab[512 + c + 6]), 0.f);
  o1.w = fmaxf(fmaf((float)h[7], ab[c + 7], ab[512 + c + 7]), 0.f);
  *(float4*)(O + e)     = o0;
  *(float4*)(O + e + 4) = o1;
}

// ---------------------------------------------------------------------------
// Launch (9 dispatches)
// ---------------------------------------------------------------------------
extern "C" void kernel_launch(void* const* d_in, const int* in_sizes, int n_in,
                              void* d_out, int out_size, void* d_ws, size_t ws_size,
                              hipStream_t stream) {
  (void)in_sizes; (void)n_in; (void)out_size; (void)ws_size;

  const float* x        = (const float*)d_in[0];
  const float* pos      = (const float*)d_in[1];
  const float* x_skip   = (const float*)d_in[3];
  const float* pos_skip = (const float*)d_in[4];
  const float* W1  = (const float*)d_in[6];
  const float* b1  = (const float*)d_in[7];
  const float* g1  = (const float*)d_in[8];
  const float* be1 = (const float*)d_in[9];
  const float* W2  = (const float*)d_in[10];
  const float* b2  = (const float*)d_in[11];
  const float* g2  = (const float*)d_in[12];
  const float* be2 = (const float*)d_in[13];
  float* out = (float*)d_out;

  char* ws = (char*)d_ws;
  // workspace layout (bytes). h2 aliases h0 (h0 dead after gemm1).
  // part1 reuses the idx3/w3 region (dead after gather_interp).
  __bf16* h0   = (__bf16*)(ws);                          // 100,663,296  h0 [65536,768]
  __bf16* h2   = (__bf16*)(ws);                          //  67,108,864  h2 [65536,512]
  __bf16* h1   = (__bf16*)(ws + 100663296ull);           //  67,108,864  h1 [65536,512] (RAW gemm1 out)
  __bf16* W1t  = (__bf16*)(ws + 167772160ull);           //     786,432  [512,768]
  __bf16* W2t  = (__bf16*)(ws + 168558592ull);           //     524,288  [512,512]
  float*  ab1   = (float*)(ws + 169086976ull);           //       4,096
  float*  ab2   = (float*)(ws + 169095168ull);           //       4,096
  int4*   idx3  = (int4*)(ws + 169099264ull);            //   1,048,576  [65536]
  float4* w3    = (float4*)(ws + 170147840ull);          //   1,048,576  [65536]
  float*  part1 = (float*)(ws + 169099264ull);           //   1,048,576  aliases idx3
  float*  part2 = (float*)(ws + 171196416ull);           //      65,536  [16][1024]

  // prep: knn (1024 blocks) + both weight transposes (2560 blocks)
  prep_kernel<<<1024 + (D_IN * C_OUT + C_OUT * C_OUT + 255) / 256, 256, 0, stream>>>(
      pos, pos_skip, idx3, w3, W1, W2, W1t, W2t);

  // gather+concat -> h0
  gather_interp<<<NF_TOT / 4, 256, 0, stream>>>(x, x_skip, idx3, w3, h0);

  // layer 1: gemm (+fused partial stats) -> reduce -> bn coeffs
  gemm_bt<D_IN, false><<<512, 512, 0, stream>>>(h0, W1t, b1, h1, part1, nullptr);
  reduce_partials<<<16, 256, 0, stream>>>(part1, part2);
  finalize_stats<<<2, 256, 0, stream>>>(part2, g1, be1, ab1, 1.0f / (float)NF_TOT);

  // layer 2: gemm with BN1+ReLU fused into A-staging -> bf16 h2 (+stats)
  gemm_bt<C_OUT, true><<<512, 512, 0, stream>>>(h1, W2t, b2, h2, part1, ab1);
  reduce_partials<<<16, 256, 0, stream>>>(part1, part2);
  finalize_stats<<<2, 256, 0, stream>>>(part2, g2, be2, ab2, 1.0f / (float)NF_TOT);

  // BN2+ReLU -> f32 out, plus pos_skip/batch tail in extra blocks
  bnrelu_tail<<<16384 + 1024, 256, 0, stream>>>(
      h2, ab2, out, pos_skip, out + (size_t)NF_TOT * 512);
}

// Round 7
// 455.537 us; speedup vs baseline: 1.0922x; 1.0160x over previous
//
#include <hip/hip_runtime.h>
#include <cstdint>
#include <cstddef>

// ---------------------------------------------------------------------------
// Problem constants (FeaturePropagationModule)
// ---------------------------------------------------------------------------
#define BATCHES   16
#define NC_PER    1024
#define NF_PER    4096
#define NC_TOT    (BATCHES * NC_PER)     // 16384
#define NF_TOT    (BATCHES * NF_PER)     // 65536
#define C_IN      512
#define C_SKIP    256
#define D_IN      (C_IN + C_SKIP)        // 768
#define C_OUT     512
#define BN_EPS    1e-5f

typedef __bf16 bf16x8 __attribute__((ext_vector_type(8)));
typedef __bf16 bf16x4 __attribute__((ext_vector_type(4)));
typedef float  f32x4  __attribute__((ext_vector_type(4)));

static_assert(sizeof(__bf16) == 2, "bf16 size");

// inline-asm 16B global load: issue point is pinned by surrounding volatile
// fences; completion is guaranteed ONLY by our manual counted vmcnt.
__device__ __forceinline__ bf16x8 load16(const __bf16* p) {
  f32x4 r;
  asm volatile("global_load_dwordx4 %0, %1, off" : "=v"(r) : "v"(p));
  union { f32x4 f; bf16x8 b; } u; u.f = r; return u.b;
}

// ---------------------------------------------------------------------------
// Kernel 1: prep = knn (blocks 0..1023) + both weight transposes
// (blocks 1024..3583). Independent work fused to cut launches.
//
// knn part: per-batch 3-NN (segmented scan, 4 segments of 256 per point).
// Distances replicate the numpy-fp32 oracle BIT-EXACTLY (per-op __f*_rn,
// numpy association order); lexicographic merge == stable ascending scan.
// ---------------------------------------------------------------------------
__global__ __launch_bounds__(256) void prep_kernel(
    const float* __restrict__ pos,      // [NC_TOT, 3]
    const float* __restrict__ pos_skip, // [NF_TOT, 3]
    int4*  __restrict__ idx3,           // [NF_TOT]
    float4* __restrict__ w3,            // [NF_TOT]
    const float* __restrict__ W1, const float* __restrict__ W2,
    __bf16* __restrict__ W1t, __bf16* __restrict__ W2t)
{
  __shared__ float s_pos[NC_PER * 3];   // 12 KiB
  __shared__ float s_pc2[NC_PER];       // 4 KiB
  __shared__ float s_pd[4][64][3];      // 3 KiB
  __shared__ int   s_pi[4][64][3];      // 3 KiB

  const int tid = threadIdx.x;

  if (blockIdx.x >= 1024) {             // ---- transpose part ----
    int idx = (blockIdx.x - 1024) * 256 + tid;
    if (idx < D_IN * C_OUT) {               // W1: K=768, N=512
      int n = idx / D_IN, k = idx - n * D_IN;
      W1t[idx] = (__bf16)W1[k * C_OUT + n];
    } else {
      idx -= D_IN * C_OUT;
      if (idx < C_OUT * C_OUT) {            // W2: K=512, N=512
        int n = idx >> 9, k = idx & 511;
        W2t[idx] = (__bf16)W2[k * C_OUT + n];
      }
    }
    return;
  }

  // ---- knn part (1024 blocks) ----
  const int bi    = blockIdx.x;
  const int fbase = bi * 64;
  const int b     = fbase >> 12;        // / NF_PER
  const int cbase = b * NC_PER;

  for (int i = tid; i < NC_PER * 3; i += 256)
    s_pos[i] = pos[(size_t)cbase * 3 + i];
  __syncthreads();
  for (int j = tid; j < NC_PER; j += 256) {
    float cx = s_pos[j * 3 + 0], cy = s_pos[j * 3 + 1], cz = s_pos[j * 3 + 2];
    s_pc2[j] = __fadd_rn(__fadd_rn(__fmul_rn(cx, cx), __fmul_rn(cy, cy)),
                         __fmul_rn(cz, cz));
  }
  __syncthreads();

  const int p   = tid & 63;
  const int seg = tid >> 6;
  const int f   = fbase + p;
  const float px = pos_skip[f * 3 + 0];
  const float py = pos_skip[f * 3 + 1];
  const float pz = pos_skip[f * 3 + 2];
  const float pf2 = __fadd_rn(__fadd_rn(__fmul_rn(px, px), __fmul_rn(py, py)),
                              __fmul_rn(pz, pz));
  float b0 = 1e30f, b1 = 1e30f, b2 = 1e30f;
  int   i0 = 0,     i1 = 0,     i2 = 0;
  const int j0 = seg * 256;
#pragma unroll 4
  for (int jj = 0; jj < 256; ++jj) {
    const int j = j0 + jj;
    float cx = s_pos[j * 3 + 0], cy = s_pos[j * 3 + 1], cz = s_pos[j * 3 + 2];
    float dot = __fadd_rn(__fadd_rn(__fmul_rn(px, cx), __fmul_rn(py, cy)),
                          __fmul_rn(pz, cz));
    float d2 = __fsub_rn(__fadd_rn(pf2, s_pc2[j]), __fmul_rn(2.0f, dot));
    if (d2 < b2) {                       // strict < keeps earliest (lowest j)
      if (d2 < b1) {
        b2 = b1; i2 = i1;
        if (d2 < b0) { b1 = b0; i1 = i0; b0 = d2; i0 = j; }
        else         { b1 = d2; i1 = j; }
      } else { b2 = d2; i2 = j; }
    }
  }
  s_pd[seg][p][0] = b0; s_pd[seg][p][1] = b1; s_pd[seg][p][2] = b2;
  s_pi[seg][p][0] = i0; s_pi[seg][p][1] = i1; s_pi[seg][p][2] = i2;
  __syncthreads();

  if (tid < 64) {
    float m0 = 1e30f, m1 = 1e30f, m2 = 1e30f;
    int  mi0 = 0,    mi1 = 0,    mi2 = 0;
#pragma unroll
    for (int s = 0; s < 4; ++s)
#pragma unroll
      for (int k = 0; k < 3; ++k) {
        float d = s_pd[s][tid][k];
        int   i = s_pi[s][tid][k];
        if (d < m2 || (d == m2 && i < mi2)) {
          if (d < m1 || (d == m1 && i < mi1)) {
            m2 = m1; mi2 = mi1;
            if (d < m0 || (d == m0 && i < mi0)) {
              m1 = m0; mi1 = mi0; m0 = d; mi0 = i;
            } else { m1 = d; mi1 = i; }
          } else { m2 = d; mi2 = i; }
        }
      }
    float w0 = 1.0f / fmaxf(m0, 1e-16f);
    float w1 = 1.0f / fmaxf(m1, 1e-16f);
    float w2 = 1.0f / fmaxf(m2, 1e-16f);
    float inv = 1.0f / __fadd_rn(__fadd_rn(w0, w1), w2);
    const int fo = fbase + tid;
    idx3[fo] = make_int4(mi0, mi1, mi2, 0);
    w3[fo]   = make_float4(w0 * inv, w1 * inv, w2 * inv, 0.f);
  }
}

// ---------------------------------------------------------------------------
// Kernel 2: gather + weighted sum + concat skip -> h0 bf16.
// One wave per fine point; XCD swizzle keeps each XCD's 2 x-slabs in its L2.
// ---------------------------------------------------------------------------
__global__ __launch_bounds__(256) void gather_interp(
    const float* __restrict__ x,        // [NC_TOT, C_IN]
    const float* __restrict__ x_skip,   // [NF_TOT, C_SKIP]
    const int4*  __restrict__ idx3,     // [NF_TOT]
    const float4* __restrict__ w3,      // [NF_TOT]
    __bf16* __restrict__ h0)            // [NF_TOT, D_IN]
{
  const int bi   = blockIdx.x;          // 16384 blocks
  const int xcd  = bi & 7;
  const int slot = bi >> 3;             // 0..2047
  const int batch = xcd * 2 + (slot >> 10);
  const int blk   = slot & 1023;
  const int wv = threadIdx.x >> 6, ln = threadIdx.x & 63;
  const int f = batch * NF_PER + blk * 4 + wv;
  const int cbase = batch * NC_PER;

  const int4   id = idx3[f];
  const float4 w  = w3[f];
  const float* x0 = x + (size_t)(cbase + id.x) * C_IN;
  const float* x1 = x + (size_t)(cbase + id.y) * C_IN;
  const float* x2 = x + (size_t)(cbase + id.z) * C_IN;
  __bf16* o = h0 + (size_t)f * D_IN;
  const int c0 = ln * 4;
#pragma unroll
  for (int it = 0; it < 2; ++it) {
    const int c = c0 + it * 256;
    float4 a0 = *(const float4*)(x0 + c);
    float4 a1 = *(const float4*)(x1 + c);
    float4 a2 = *(const float4*)(x2 + c);
    bf16x4 ov;
    ov[0] = (__bf16)(w.x * a0.x + w.y * a1.x + w.z * a2.x);
    ov[1] = (__bf16)(w.x * a0.y + w.y * a1.y + w.z * a2.y);
    ov[2] = (__bf16)(w.x * a0.z + w.y * a1.z + w.z * a2.z);
    ov[3] = (__bf16)(w.x * a0.w + w.y * a1.w + w.z * a2.w);
    *(bf16x4*)(o + c) = ov;
  }
  float4 s = *(const float4*)(x_skip + (size_t)f * C_SKIP + c0);
  bf16x4 sv;
  sv[0] = (__bf16)s.x; sv[1] = (__bf16)s.y;
  sv[2] = (__bf16)s.z; sv[3] = (__bf16)s.w;
  *(bf16x4*)(o + C_IN + c0) = sv;
}

// ---------------------------------------------------------------------------
// Kernel 3 (R9, resubmit): occupancy-doubled GEMM. 256x128 tile, BK=32,
// 8 waves of 64x64 (acc = 64 f32/wave -> <=128 unified regs -> 16 waves/CU),
// LDS 56 KB (-> 2 blocks/CU). Grid 1024 blocks = fully co-resident;
// inter-block overlap hides barrier/vmcnt drains (the 1-block/CU config was
// pinned at 21% occupancy / 23% MfmaUtil across three schedule variants).
// Counted-vmcnt pipeline and both-sides XOR swizzle retained.
//  - FUSE_BN (gemm2): A reg-staged (2 asm loads/tile), BN1+ReLU applied,
//    ds_write into swizzled LDS; B via global_load_lds DMA.
//  - Epilogue: stats 4-way wm-combine; C repack through the 32 KB As
//    region in two 128-row rounds, then bf16x8 coalesced stores.
// ---------------------------------------------------------------------------
template <int K, bool FUSE_BN>
__global__ __launch_bounds__(512, 4) void gemm_bt(
    const __bf16* __restrict__ A,    // [M, K]
    const __bf16* __restrict__ Bt,   // [512, K]
    const float*  __restrict__ bias, // [512]
    __bf16* __restrict__ Cout,       // [M, 512]
    float* __restrict__ part1,       // [256][1024] per-mblock partials
    const float* __restrict__ ab)    // [1024] BN a/b (FUSE_BN only)
{
  constexpr int NT = K / 32;                      // 24 (gemm1) / 16 (gemm2)
  __shared__ __align__(16) __bf16 As[2][8192];    // [buf][256*32]  32 KB
  __shared__ __align__(16) __bf16 Bs[2][4096];    // [buf][128*32]  16 KB
  __shared__ float s_red[4][2][4][16][2];         // [wm][wn][nf][l16][s/ss]
  __shared__ float s_ab[1024];                    // BN coeffs (FUSE_BN)

  const int tid  = threadIdx.x;
  const int wave = tid >> 6, lane = tid & 63;
  const int quad = lane >> 4, l16 = lane & 15;
  const int wm = wave >> 1, wn = wave & 1;        // 4 x 2 wave grid, 64x64 ea

  // T1: XCD-chunked bijective work map (1024 % 8 == 0).
  const int bid  = blockIdx.x;
  const int work = (bid & 7) * 128 + (bid >> 3);
  const int mt = work >> 2, nt = work & 3;
  const int m0 = mt * 256, n0 = nt * 128;

  // ---- staging geometry (both-sides XOR swizzle, rule 21) -----------------
  // chunk c = pass*512+tid; row = c>>2, slot = c&3; LDS dest linear c*16B;
  // source col = (slot ^ ((row>>1)&3))*8 elems. (row>>1)&3 == (tid>>3)&3 for
  // both A passes (row += 128 preserves it).
  const int srow  = tid >> 2;                               // 0..127
  const int colSw = (((tid & 3) ^ ((tid >> 3) & 3)) << 3);  // elems

  auto stageA = [&](int t, int buf) {
#pragma unroll
    for (int p = 0; p < 2; ++p)
      __builtin_amdgcn_global_load_lds(
          (const __attribute__((address_space(1))) unsigned int*)(
              A + (size_t)(m0 + p * 128 + srow) * K + t * 32 + colSw),
          (__attribute__((address_space(3))) unsigned int*)(
              &As[buf][p * 4096 + tid * 8]),
          16, 0, 0);
  };
  auto stageB = [&](int t, int buf) {
    __builtin_amdgcn_global_load_lds(
        (const __attribute__((address_space(1))) unsigned int*)(
            Bt + (size_t)(n0 + srow) * K + t * 32 + colSw),
        (__attribute__((address_space(3))) unsigned int*)(
            &Bs[buf][tid * 8]),
        16, 0, 0);
  };

  bf16x8 ar[2];  // FUSE_BN in-flight A (rows srow, srow+128)
  auto load_a_regs = [&](int t) {
#pragma unroll
    for (int p = 0; p < 2; ++p)
      ar[p] = load16(A + (size_t)(m0 + p * 128 + srow) * K + t * 32 + colSw);
  };
  auto bn_write_A = [&](int t, int buf) {
    const int cb = t * 32 + colSw;
    const float4 aL = *(const float4*)&s_ab[cb];
    const float4 aH = *(const float4*)&s_ab[cb + 4];
    const float4 bL = *(const float4*)&s_ab[512 + cb];
    const float4 bH = *(const float4*)&s_ab[512 + cb + 4];
#pragma unroll
    for (int p = 0; p < 2; ++p) {
      bf16x8 v = ar[p]; bf16x8 o;
      o[0] = (__bf16)fmaxf(fmaf((float)v[0], aL.x, bL.x), 0.f);
      o[1] = (__bf16)fmaxf(fmaf((float)v[1], aL.y, bL.y), 0.f);
      o[2] = (__bf16)fmaxf(fmaf((float)v[2], aL.z, bL.z), 0.f);
      o[3] = (__bf16)fmaxf(fmaf((float)v[3], aL.w, bL.w), 0.f);
      o[4] = (__bf16)fmaxf(fmaf((float)v[4], aH.x, bH.x), 0.f);
      o[5] = (__bf16)fmaxf(fmaf((float)v[5], aH.y, bH.y), 0.f);
      o[6] = (__bf16)fmaxf(fmaf((float)v[6], aH.z, bH.z), 0.f);
      o[7] = (__bf16)fmaxf(fmaf((float)v[7], aH.w, bH.w), 0.f);
      *(bf16x8*)&As[buf][p * 4096 + tid * 8] = o;
    }
  };

  f32x4 acc[4][4] = {};

  // ---- prologue: K-tile 0 -> buf 0 ----------------------------------------
  if constexpr (FUSE_BN) {
    for (int i = tid; i < 1024; i += 512) s_ab[i] = ab[i];
    load_a_regs(0);                       // 2 asm loads
    stageB(0, 0);                         // 1 DMA
    __syncthreads();                      // vmcnt(0)+lgkm; s_ab visible
    bn_write_A(0, 0);
    asm volatile("s_waitcnt lgkmcnt(0)" ::: "memory");
    __builtin_amdgcn_sched_barrier(0);
    __builtin_amdgcn_s_barrier();
  } else {
    stageA(0, 0);
    stageB(0, 0);
  }

  for (int t = 0; t < NT; ++t) {
    const int cur = t & 1;

    // stage next tile, counted drain of current tile's loads
    if (t + 1 < NT) {
      if constexpr (FUSE_BN) {
        load_a_regs(t + 1);                              // 2 asm loads
        stageB(t + 1, cur ^ 1);                          // 1 DMA
        asm volatile("s_waitcnt vmcnt(3)" ::: "memory"); // drain B(t)
      } else {
        stageA(t + 1, cur ^ 1);                          // 2 DMA
        stageB(t + 1, cur ^ 1);                          // 1 DMA
        asm volatile("s_waitcnt vmcnt(3)" ::: "memory"); // drain tile t's 3
      }
    } else {
      asm volatile("s_waitcnt vmcnt(0)" ::: "memory");   // last tile drains
    }
    __builtin_amdgcn_sched_barrier(0);
    __builtin_amdgcn_s_barrier();

    bf16x8 aA[4], bB[4];
#pragma unroll
    for (int mf = 0; mf < 4; ++mf) {
      const int row = wm * 64 + mf * 16 + l16;
      aA[mf] = *(const bf16x8*)&As[cur][row * 32 +
                                        ((quad ^ ((row >> 1) & 3)) << 3)];
    }
#pragma unroll
    for (int nf = 0; nf < 4; ++nf) {
      const int row = wn * 64 + nf * 16 + l16;
      bB[nf] = *(const bf16x8*)&Bs[cur][row * 32 +
                                        ((quad ^ ((row >> 1) & 3)) << 3)];
    }
    __builtin_amdgcn_s_setprio(1);
#pragma unroll
    for (int mf = 0; mf < 4; ++mf)
#pragma unroll
      for (int nf = 0; nf < 4; ++nf)
        acc[mf][nf] = __builtin_amdgcn_mfma_f32_16x16x32_bf16(
            aA[mf], bB[nf], acc[mf][nf], 0, 0, 0);
    __builtin_amdgcn_s_setprio(0);

    if constexpr (FUSE_BN) {
      if (t + 1 < NT) {
        asm volatile("s_waitcnt vmcnt(1)" ::: "memory"); // drain A(t+1) regs
        __builtin_amdgcn_sched_barrier(0);
        bn_write_A(t + 1, cur ^ 1);
        asm volatile("s_waitcnt lgkmcnt(0)" ::: "memory");
        __builtin_amdgcn_sched_barrier(0);
      }
    }
    __builtin_amdgcn_s_barrier();
  }

  // ---- epilogue -----------------------------------------------------------
  // stats (C/D layout m89/m91: n = l16, m = quad*4 + r)
  float sArr[4], ssArr[4];
#pragma unroll
  for (int nf = 0; nf < 4; ++nf) {
    const float bv = bias[n0 + wn * 64 + nf * 16 + l16];
    float s = 0.f, ss = 0.f;
#pragma unroll
    for (int mf = 0; mf < 4; ++mf)
#pragma unroll
      for (int r = 0; r < 4; ++r) {
        const float v = acc[mf][nf][r] + bv;
        s += v; ss += v * v;
      }
    s  += __shfl_down(s, 32);  s  += __shfl_down(s, 16);
    ss += __shfl_down(ss, 32); ss += __shfl_down(ss, 16);
    sArr[nf] = s; ssArr[nf] = ss;
  }
  if (quad == 0) {
#pragma unroll
    for (int nf = 0; nf < 4; ++nf) {
      s_red[wm][wn][nf][l16][0] = sArr[nf];
      s_red[wm][wn][nf][l16][1] = ssArr[nf];
    }
  }

  // C repack through As (32 KB = one 128x128 half-tile), 2 rounds
  __bf16* Aflat = &As[0][0];
#pragma unroll
  for (int r = 0; r < 2; ++r) {
    __syncthreads();                       // prior reads of As done
    if ((wm >> 1) == r) {
      const int rbase = (wm & 1) * 64;     // local row base in this half
#pragma unroll
      for (int nf = 0; nf < 4; ++nf) {
        const int cl = wn * 64 + nf * 16 + l16;
        const float bv = bias[n0 + cl];
        const int cw = cl ^ (quad << 4);   // conflict-free b16 writes
#pragma unroll
        for (int mf = 0; mf < 4; ++mf) {
          const int rl = rbase + mf * 16 + quad * 4;
#pragma unroll
          for (int rr = 0; rr < 4; ++rr)
            Aflat[(rl + rr) * 128 + cw] = (__bf16)(acc[mf][nf][rr] + bv);
        }
      }
    }
    __syncthreads();
    // coalesced store: 4 passes x 512 thr x 16B = 128x128 bf16
#pragma unroll
    for (int p = 0; p < 4; ++p) {
      const int i   = p * 512 + tid;
      const int row = i >> 4;              // 0..127
      const int cc  = (i & 15) * 8;        // elem col base
      bf16x8 v = *(const bf16x8*)&Aflat[row * 128 +
                                        (cc ^ (((row >> 2) & 3) << 4))];
      *(bf16x8*)&Cout[(size_t)(m0 + r * 128 + row) * 512 + n0 + cc] = v;
    }
  }

  // part1: combine the 4 wm-waves' partials (s_red barriered above)
  if (wm == 0 && quad == 0) {
    float* rowp = part1 + (size_t)mt * 1024;
#pragma unroll
    for (int nf = 0; nf < 4; ++nf) {
      const int n = n0 + wn * 64 + nf * 16 + l16;
      float s = 0.f, ss = 0.f;
#pragma unroll
      for (int w = 0; w < 4; ++w) {
        s  += s_red[w][wn][nf][l16][0];
        ss += s_red[w][wn][nf][l16][1];
      }
      rowp[n]       = s;
      rowp[512 + n] = ss;
    }
  }
}

// ---------------------------------------------------------------------------
// Stage A: fold part1[256][1024] -> part2[16][1024] (coalesced, 16 blocks)
// ---------------------------------------------------------------------------
__global__ __launch_bounds__(256) void reduce_partials(
    const float* __restrict__ part1, float* __restrict__ part2) {
  const int rb = blockIdx.x;            // 16 blocks, 16 rows each
  const int t  = threadIdx.x;
#pragma unroll
  for (int k = 0; k < 4; ++k) {
    const int c = k * 256 + t;
    float acc = 0.f;
    const float* p = part1 + (size_t)rb * 16 * 1024 + c;
#pragma unroll
    for (int r = 0; r < 16; ++r) { acc += *p; p += 1024; }
    part2[rb * 1024 + c] = acc;
  }
}

// ab layout: [0,512) = scale a, [512,1024) = shift b:  y = a*h + b
__global__ void finalize_stats(const float* __restrict__ part2,
                               const float* __restrict__ g,
                               const float* __restrict__ be,
                               float* __restrict__ ab, float invM) {
  const int c = blockIdx.x * 256 + threadIdx.x;
  if (c < 512) {
    float s = 0.f, ss = 0.f;
#pragma unroll
    for (int r = 0; r < 16; ++r) {
      s  += part2[r * 1024 + c];
      ss += part2[r * 1024 + 512 + c];
    }
    float mean = s * invM;
    float var  = ss * invM - mean * mean;
    float a = g[c] * rsqrtf(var + BN_EPS);
    ab[c] = a;
    ab[512 + c] = be[c] - mean * a;
  }
}

// ---------------------------------------------------------------------------
// Kernel 5: BN+ReLU (bf16 h2 -> f32 out, 8 elems/thread) + tail
// (pos_skip copy + batch ids) in the same launch (extra 1024 blocks).
// ---------------------------------------------------------------------------
__global__ __launch_bounds__(256) void bnrelu_tail(
    const __bf16* __restrict__ H, const float* __restrict__ ab,
    float* __restrict__ O,
    const float* __restrict__ pos_skip, float* __restrict__ out2) {
  if (blockIdx.x >= 16384) {              // ---- tail part ----
    const int i = (blockIdx.x - 16384) * 256 + threadIdx.x;  // 0..262143
    if (i < NF_TOT * 3) {
      out2[i] = pos_skip[i];
    } else {
      const int f = i - NF_TOT * 3;
      out2[i] = (float)(f >> 12);         // f / NF_PER
    }
    return;
  }
  const size_t e = ((size_t)blockIdx.x * 256 + threadIdx.x) * 8;
  const int c = (int)(e & 511);
  bf16x8 h = *(const bf16x8*)(H + e);
  float4 o0, o1;
  o0.x = fmaxf(fmaf((float)h[0], ab[c + 0], ab[512 + c + 0]), 0.f);
  o0.y = fmaxf(fmaf((float)h[1], ab[c + 1], ab[512 + c + 1]), 0.f);
  o0.z = fmaxf(fmaf((float)h[2], ab[c + 2], ab[512 + c + 2]), 0.f);
  o0.w = fmaxf(fmaf((float)h[3], ab[c + 3], ab[512 + c + 3]), 0.f);
  o1.x = fmaxf(fmaf((float)h[4], ab[c + 4], ab[512 + c + 4]), 0.f);
  o1.y = fmaxf(fmaf((float)h[5], ab[c + 5], ab[512 + c + 5]), 0.f);
  o1.z = fmaxf(fmaf((float)h[6], ab[c + 6], ab[512 + c + 6]), 0.f);
  o1.w = fmaxf(fmaf((float)h[7], ab[c + 7], ab[512 + c + 7]), 0.f);
  *(float4*)(O + e)     = o0;
  *(float4*)(O + e + 4) = o1;
}

// ---------------------------------------------------------------------------
// Launch (9 dispatches)
// ---------------------------------------------------------------------------
extern "C" void kernel_launch(void* const* d_in, const int* in_sizes, int n_in,
                              void* d_out, int out_size, void* d_ws, size_t ws_size,
                              hipStream_t stream) {
  (void)in_sizes; (void)n_in; (void)out_size; (void)ws_size;

  const float* x        = (const float*)d_in[0];
  const float* pos      = (const float*)d_in[1];
  const float* x_skip   = (const float*)d_in[3];
  const float* pos_skip = (const float*)d_in[4];
  const float* W1  = (const float*)d_in[6];
  const float* b1  = (const float*)d_in[7];
  const float* g1  = (const float*)d_in[8];
  const float* be1 = (const float*)d_in[9];
  const float* W2  = (const float*)d_in[10];
  const float* b2  = (const float*)d_in[11];
  const float* g2  = (const float*)d_in[12];
  const float* be2 = (const float*)d_in[13];
  float* out = (float*)d_out;

  char* ws = (char*)d_ws;
  // workspace layout (bytes). h2 aliases h0 (h0 dead after gemm1).
  // part1 reuses the idx3 region (dead after gather_interp).
  __bf16* h0   = (__bf16*)(ws);                          // 100,663,296  h0 [65536,768]
  __bf16* h2   = (__bf16*)(ws);                          //  67,108,864  h2 [65536,512]
  __bf16* h1   = (__bf16*)(ws + 100663296ull);           //  67,108,864  h1 [65536,512] (RAW gemm1 out)
  __bf16* W1t  = (__bf16*)(ws + 167772160ull);           //     786,432  [512,768]
  __bf16* W2t  = (__bf16*)(ws + 168558592ull);           //     524,288  [512,512]
  float*  ab1   = (float*)(ws + 169086976ull);           //       4,096
  float*  ab2   = (float*)(ws + 169095168ull);           //       4,096
  int4*   idx3  = (int4*)(ws + 169099264ull);            //   1,048,576  [65536]
  float4* w3    = (float4*)(ws + 170147840ull);          //   1,048,576  [65536]
  float*  part1 = (float*)(ws + 169099264ull);           //   1,048,576  aliases idx3
  float*  part2 = (float*)(ws + 171196416ull);           //      65,536  [16][1024]

  // prep: knn (1024 blocks) + both weight transposes (2560 blocks)
  prep_kernel<<<1024 + (D_IN * C_OUT + C_OUT * C_OUT + 255) / 256, 256, 0, stream>>>(
      pos, pos_skip, idx3, w3, W1, W2, W1t, W2t);

  // gather+concat -> h0
  gather_interp<<<NF_TOT / 4, 256, 0, stream>>>(x, x_skip, idx3, w3, h0);

  // layer 1: gemm (+fused partial stats) -> reduce -> bn coeffs
  gemm_bt<D_IN, false><<<1024, 512, 0, stream>>>(h0, W1t, b1, h1, part1, nullptr);
  reduce_partials<<<16, 256, 0, stream>>>(part1, part2);
  finalize_stats<<<2, 256, 0, stream>>>(part2, g1, be1, ab1, 1.0f / (float)NF_TOT);

  // layer 2: gemm with BN1+ReLU fused into A-staging -> bf16 h2 (+stats)
  gemm_bt<C_OUT, true><<<1024, 512, 0, stream>>>(h1, W2t, b2, h2, part1, ab1);
  reduce_partials<<<16, 256, 0, stream>>>(part1, part2);
  finalize_stats<<<2, 256, 0, stream>>>(part2, g2, be2, ab2, 1.0f / (float)NF_TOT);

  // BN2+ReLU -> f32 out, plus pos_skip/batch tail in extra blocks
  bnrelu_tail<<<16384 + 1024, 256, 0, stream>>>(
      h2, ab2, out, pos_skip, out + (size_t)NF_TOT * 512);
}